// Round 3
// baseline (865.121 us; speedup 1.0000x reference)
//
#include <hip/hip_runtime.h>

// NearestMean: out = labels[searchsorted(thresholds, X, side='right')]
// X: fp32, 142,848,000 elems (16x240x240x155). thresholds: 3 fp32.
// labels: 4 int32 -> {0,1,2,4}. out: int32.
//
// Pure streaming, memory-bound. Mandatory traffic = 571 MB read + 571 MB
// write = 1.143 GB -> ~184 us floor at 6.2 TB/s achieved-fill rate.
// R3: same as R2 but with native clang vectors (ext_vector_type) so the
// nontemporal builtins accept them (HIP_vector_type structs are rejected).

typedef float floatx4 __attribute__((ext_vector_type(4)));
typedef int   intx4   __attribute__((ext_vector_type(4)));

__global__ __launch_bounds__(256) void NearestMean_kernel(
    const floatx4* __restrict__ x4,
    const float* __restrict__ thr,
    const int* __restrict__ labs,
    intx4* __restrict__ out4,
    long long n4)                      // number of float4 elements
{
    const float t0 = thr[0], t1 = thr[1], t2 = thr[2];
    const int   l0 = labs[0], l1 = labs[1], l2 = labs[2], l3 = labs[3];

    // Block covers 2*256 float4s. Thread handles base+tid and base+tid+256
    // -> every load/store instruction is 16 B/lane contiguous across the wave.
    long long base = (long long)blockIdx.x * (2 * 256) + threadIdx.x;

    #pragma unroll
    for (int rep = 0; rep < 2; ++rep) {
        long long i = base + rep * 256;
        if (i < n4) {
            floatx4 v = __builtin_nontemporal_load(&x4[i]);
            intx4 o;
            o.x = v.x >= t2 ? l3 : (v.x >= t1 ? l2 : (v.x >= t0 ? l1 : l0));
            o.y = v.y >= t2 ? l3 : (v.y >= t1 ? l2 : (v.y >= t0 ? l1 : l0));
            o.z = v.z >= t2 ? l3 : (v.z >= t1 ? l2 : (v.z >= t0 ? l1 : l0));
            o.w = v.w >= t2 ? l3 : (v.w >= t1 ? l2 : (v.w >= t0 ? l1 : l0));
            __builtin_nontemporal_store(o, &out4[i]);
        }
    }
}

// Scalar tail kernel (n % 4 != 0 — not hit for this shape, kept for safety).
__global__ __launch_bounds__(64) void NearestMean_tail(
    const float* __restrict__ x,
    const float* __restrict__ thr,
    const int* __restrict__ labs,
    int* __restrict__ out,
    long long start, long long n)
{
    long long i = start + threadIdx.x;
    if (i < n) {
        const float t0 = thr[0], t1 = thr[1], t2 = thr[2];
        const int   l0 = labs[0], l1 = labs[1], l2 = labs[2], l3 = labs[3];
        float v = x[i];
        out[i] = v >= t2 ? l3 : (v >= t1 ? l2 : (v >= t0 ? l1 : l0));
    }
}

extern "C" void kernel_launch(void* const* d_in, const int* in_sizes, int n_in,
                              void* d_out, int out_size, void* d_ws, size_t ws_size,
                              hipStream_t stream) {
    const float* X    = (const float*)d_in[0];
    const float* thr  = (const float*)d_in[1];
    const int*   labs = (const int*)d_in[2];
    int* out = (int*)d_out;

    long long n  = (long long)in_sizes[0];
    long long n4 = n / 4;

    const int block = 256;
    const long long per_block = 2 * block;              // 512 float4 / block
    long long grid = (n4 + per_block - 1) / per_block;
    if (grid < 1) grid = 1;

    NearestMean_kernel<<<(dim3)(unsigned)grid, block, 0, stream>>>(
        (const floatx4*)X, thr, labs, (intx4*)out, n4);

    if (n4 * 4 < n) {
        NearestMean_tail<<<1, 64, 0, stream>>>(X, thr, labs, out, n4 * 4, n);
    }
}